// Round 6
// baseline (1672.108 us; speedup 1.0000x reference)
//
#include <hip/hip_runtime.h>
#include <stdint.h>

#define NB 128   // batch
#define NT 512   // time steps
#define NI 256   // input dim
#define NH 512   // hidden dim
#define NO 256   // output dim

// ---------- bf16 helpers ----------
__device__ __forceinline__ uint16_t f2bf(float x) {
  uint32_t u = __float_as_uint(x);
  return (uint16_t)((u + 0x7fffu + ((u >> 16) & 1u)) >> 16);
}
__device__ __forceinline__ uint32_t pack2bf(float a, float b) {
  return (uint32_t)f2bf(a) | ((uint32_t)f2bf(b) << 16);
}

#if __has_builtin(__builtin_amdgcn_fdot2_f32_bf16)
typedef __bf16 bf16x2_t __attribute__((ext_vector_type(2)));
#define HAVE_DOT2 1
#endif

__device__ __forceinline__ float dot2bf(uint32_t w, uint32_t h, float acc) {
#ifdef HAVE_DOT2
  return __builtin_amdgcn_fdot2_f32_bf16(__builtin_bit_cast(bf16x2_t, w),
                                         __builtin_bit_cast(bf16x2_t, h), acc, false);
#else
  float wl = __uint_as_float(w << 16), wh = __uint_as_float(w & 0xffff0000u);
  float hl = __uint_as_float(h << 16), hh = __uint_as_float(h & 0xffff0000u);
  return fmaf(wh, hh, fmaf(wl, hl, acc));
#endif
}

__device__ __forceinline__ float dot4x(uint4 w, uint4 h, float a) {
  a = dot2bf(w.x, h.x, a);
  a = dot2bf(w.y, h.y, a);
  a = dot2bf(w.z, h.z, a);
  a = dot2bf(w.w, h.w, a);
  return a;
}

__device__ __forceinline__ float fast_tanh(float x) {
  float e = __expf(2.0f * x);
#if __has_builtin(__builtin_amdgcn_rcpf)
  return 1.0f - 2.0f * __builtin_amdgcn_rcpf(e + 1.0f);
#else
  return 1.0f - 2.0f / (e + 1.0f);
#endif
}

typedef __bf16 bf16x8 __attribute__((ext_vector_type(8)));
typedef float f32x4 __attribute__((ext_vector_type(4)));

// ---------- kernel 0: pack W_hh quads; Wih->bf16; transpose W_out; bias sum ----------
// Recur thread t (0..511): kq8 = t>>6 (k2 in [kq8*32,+32)), owns j = (t&63)*8 + jj (jj<8).
// Quad q = jj*8 + c (c=0..7): uint4 = bf16-pairs of W_hh[j][2*k2b..+8], k2b = kq8*32 + c*4.
// Stored at WQ[q*512 + t]. q<52 -> registers, q>=52 -> LDS in recur.
__global__ __launch_bounds__(256) void prep_kernel(const float* __restrict__ Whh,
                                                   const float* __restrict__ Wih,
                                                   const float* __restrict__ Wout,
                                                   const float* __restrict__ bih,
                                                   const float* __restrict__ bhh,
                                                   uint4* __restrict__ WQ,
                                                   float* __restrict__ WoT,
                                                   uint2* __restrict__ Wihb32,
                                                   float* __restrict__ BS) {
  int idx = blockIdx.x * 256 + threadIdx.x;
  if (idx < 32768) {                       // WQ quads
    int q = idx >> 9, t = idx & 511;
    int jj = q >> 3, c = q & 7;
    int j = (t & 63) * 8 + jj;
    int k2b = (t >> 6) * 32 + c * 4;
    const float* row = Whh + (size_t)j * NH + 2 * k2b;
    float4 f0 = *(const float4*)row;
    float4 f1 = *(const float4*)(row + 4);
    uint4 w;
    w.x = pack2bf(f0.x, f0.y);
    w.y = pack2bf(f0.z, f0.w);
    w.z = pack2bf(f1.x, f1.y);
    w.w = pack2bf(f1.z, f1.w);
    WQ[idx] = w;
  } else if (idx < 65536) {                // Wih -> bf16 (same row-major layout)
    int i = idx - 32768;
    float4 f = *(const float4*)(Wih + (size_t)i * 4);
    uint2 p;
    p.x = pack2bf(f.x, f.y);
    p.y = pack2bf(f.z, f.w);
    Wihb32[i] = p;
  } else if (idx < 98304) {                // W_out transpose (fp32)
    int i = idx - 65536;
    int o4 = (i & 63) * 4;
    int k = i >> 6;
    float4 v;
    v.x = Wout[(size_t)(o4 + 0) * NH + k];
    v.y = Wout[(size_t)(o4 + 1) * NH + k];
    v.z = Wout[(size_t)(o4 + 2) * NH + k];
    v.w = Wout[(size_t)(o4 + 3) * NH + k];
    *(float4*)&WoT[(size_t)k * NO + o4] = v;
  } else if (idx < 98816) {                // bias sum
    int n = idx - 98304;
    BS[n] = bih[n] + bhh[n];
  }
}

// ---------- kernel 1: x_proj GEMM via bf16 MFMA ----------
__global__ __launch_bounds__(256, 2) void xproj_kernel(const float* __restrict__ A,
                                                       const uint16_t* __restrict__ Wihb,
                                                       const float* __restrict__ BS,
                                                       uint16_t* __restrict__ XP) {
  const int w = threadIdx.x >> 6;
  const int l = threadIdx.x & 63;
  const int sl = l & 15, quad = l >> 4;
  const int m = blockIdx.x * 64 + w * 16 + sl;   // input row this lane supplies

  f32x4 acc[32] = {};
  const float* arow = A + (size_t)m * NI;

  for (int k0 = 0; k0 < NI; k0 += 32) {
    float4 f0 = *(const float4*)(arow + k0 + quad * 8);
    float4 f1 = *(const float4*)(arow + k0 + quad * 8 + 4);
    uint4 ap;
    ap.x = pack2bf(f0.x, f0.y);
    ap.y = pack2bf(f0.z, f0.w);
    ap.z = pack2bf(f1.x, f1.y);
    ap.w = pack2bf(f1.z, f1.w);
    bf16x8 afrag = __builtin_bit_cast(bf16x8, ap);
#pragma unroll
    for (int u = 0; u < 32; ++u) {
      uint4 bp = *(const uint4*)(Wihb + (size_t)(u * 16 + sl) * NI + k0 + quad * 8);
      acc[u] = __builtin_amdgcn_mfma_f32_16x16x32_bf16(
          __builtin_bit_cast(bf16x8, bp), afrag, acc[u], 0, 0, 0);
    }
  }

  uint16_t* xrow = XP + (size_t)m * NH;
#pragma unroll
  for (int u = 0; u < 32; ++u) {
    float4 bs = *(const float4*)(BS + u * 16 + quad * 4);
    uint2 pw;
    pw.x = pack2bf(acc[u][0] + bs.x, acc[u][1] + bs.y);
    pw.y = pack2bf(acc[u][2] + bs.z, acc[u][3] + bs.w);
    *(uint2*)(xrow + u * 16 + quad * 4) = pw;
  }
}

// ---------- kernel 2: recurrence, 2 batches/WG, W_hh reg(52q)+LDS(12q) ----------
// 64 WGs x 512 thr. Weight registers/LDS stream and both barriers serve TWO
// batch-steps per iteration (amortization); per-batch VALU dot work unchanged.
__global__ __launch_bounds__(512, 2) void recur_kernel(const uint4* __restrict__ WQ,
                                                       const float* __restrict__ WoT,
                                                       const uint16_t* __restrict__ XP,
                                                       const float* __restrict__ h0,
                                                       const float* __restrict__ bout,
                                                       float* __restrict__ out) {
  __shared__ uint4 WL[12][512];                    // 96 KB: quads q=52..63
  __shared__ __align__(16) uint16_t h2[2][2][NH];  // 4 KB [buf][batch][j]
  __shared__ float P[2][8][NH];                    // 32 KB [batch][kq][j]
  const int t = threadIdx.x;
  const int b0 = blockIdx.x * 2;
  const int kq8 = t >> 6;          // k-eighth
  const int jb = (t & 63) * 8;     // first owned output
  const float invT = 1.0f / (float)NT;

  uint4 Wr[52];
#pragma unroll
  for (int q = 0; q < 52; ++q) Wr[q] = WQ[q * 512 + t];
#pragma unroll
  for (int i = 0; i < 12; ++i) WL[i][t] = WQ[(52 + i) * 512 + t];

  float hjA = h0[t];
  float hjB = hjA;
  {
    uint16_t hb = f2bf(hjA);
    h2[0][0][t] = hb;
    h2[0][1][t] = hb;
  }
  __syncthreads();

  const uint16_t* xpA = XP + (size_t)b0 * NT * NH;
  const uint16_t* xpB = XP + (size_t)(b0 + 1) * NT * NH;

  for (int ts = 0; ts < NT; ++ts) {
    const int cur = ts & 1;
    float xA = __uint_as_float((uint32_t)xpA[(size_t)ts * NH + t] << 16);
    float xB = __uint_as_float((uint32_t)xpB[(size_t)ts * NH + t] << 16);

    const uint32_t* hwA = (const uint32_t*)h2[cur][0] + kq8 * 32;
    const uint32_t* hwB = (const uint32_t*)h2[cur][1] + kq8 * 32;
    float aA[8] = {}, aB[8] = {};
#pragma unroll
    for (int c = 0; c < 8; ++c) {
      uint4 hA = *(const uint4*)(hwA + c * 4);   // wave-uniform broadcast
      uint4 hB = *(const uint4*)(hwB + c * 4);
#pragma unroll
      for (int jj = 0; jj < 6; ++jj) {
        uint4 w = Wr[jj * 8 + c];
        aA[jj] = dot4x(w, hA, aA[jj]);
        aB[jj] = dot4x(w, hB, aB[jj]);
      }
      {
        uint4 w = (c < 4) ? Wr[48 + c] : WL[c - 4][t];
        aA[6] = dot4x(w, hA, aA[6]);
        aB[6] = dot4x(w, hB, aB[6]);
      }
      {
        uint4 w = WL[4 + c][t];
        aA[7] = dot4x(w, hA, aA[7]);
        aB[7] = dot4x(w, hB, aB[7]);
      }
    }
    *(float4*)&P[0][kq8][jb]     = make_float4(aA[0], aA[1], aA[2], aA[3]);
    *(float4*)&P[0][kq8][jb + 4] = make_float4(aA[4], aA[5], aA[6], aA[7]);
    *(float4*)&P[1][kq8][jb]     = make_float4(aB[0], aB[1], aB[2], aB[3]);
    *(float4*)&P[1][kq8][jb + 4] = make_float4(aB[4], aB[5], aB[6], aB[7]);
    __syncthreads();   // P visible; all h2[cur] reads done

    float yA = ((P[0][0][t] + P[0][1][t]) + (P[0][2][t] + P[0][3][t])) +
               ((P[0][4][t] + P[0][5][t]) + (P[0][6][t] + P[0][7][t]));
    float yB = ((P[1][0][t] + P[1][1][t]) + (P[1][2][t] + P[1][3][t])) +
               ((P[1][4][t] + P[1][5][t]) + (P[1][6][t] + P[1][7][t]));
    hjA = fmaf(fast_tanh(xA + yA), invT, hjA);
    hjB = fmaf(fast_tanh(xB + yB), invT, hjB);
    h2[cur ^ 1][0][t] = f2bf(hjA);
    h2[cur ^ 1][1][t] = f2bf(hjB);
    __syncthreads();   // new h visible
  }

  // stash fp32 h in P rows, then all 512 threads do readout (t<256: batch0)
  P[0][0][t] = hjA;
  P[1][0][t] = hjB;
  __syncthreads();

  {
    const int bb = t >> 8;            // 0 or 1
    const int o = t & 255;            // output index (NO=256)
    const float* hs = &P[bb][0][0];
    float c0 = 0.f, c1 = 0.f;
#pragma unroll 4
    for (int k = 0; k < NH; k += 2) {
      c0 = fmaf(WoT[(size_t)k * NO + o], hs[k], c0);
      c1 = fmaf(WoT[(size_t)(k + 1) * NO + o], hs[k + 1], c1);
    }
    out[(size_t)(b0 + bb) * NO + o] = c0 + c1 + bout[o];
  }
}

// ---------- launch ----------
extern "C" void kernel_launch(void* const* d_in, const int* in_sizes, int n_in,
                              void* d_out, int out_size, void* d_ws, size_t ws_size,
                              hipStream_t stream) {
  const float* inputs = (const float*)d_in[0];
  const float* Wih    = (const float*)d_in[1];
  const float* bih    = (const float*)d_in[2];
  const float* Whh    = (const float*)d_in[3];
  const float* bhh    = (const float*)d_in[4];
  const float* Wout   = (const float*)d_in[5];
  const float* bout   = (const float*)d_in[6];
  const float* h0     = (const float*)d_in[7];
  float* out = (float*)d_out;

  char* ws = (char*)d_ws;
  uint4*    WQ     = (uint4*)ws;                          // 512 KB
  float*    WoT    = (float*)(ws + (512u << 10));         // 512 KB
  uint2*    Wihb32 = (uint2*)(ws + (1024u << 10));        // 256 KB
  float*    BS     = (float*)(ws + (1280u << 10));        // 2 KB
  uint16_t* XP     = (uint16_t*)(ws + (1536u << 10));     // 64 MB

  hipLaunchKernelGGL(prep_kernel, dim3(386), dim3(256), 0, stream,
                     Whh, Wih, Wout, bih, bhh, WQ, WoT, Wihb32, BS);
  hipLaunchKernelGGL(xproj_kernel, dim3(NB * NT / 64), dim3(256), 0, stream,
                     inputs, (const uint16_t*)Wihb32, BS, XP);
  hipLaunchKernelGGL(recur_kernel, dim3(NB / 2), dim3(512), 0, stream,
                     WQ, WoT, XP, h0, bout, out);
}

// Round 7
// 943.177 us; speedup vs baseline: 1.7728x; 1.7728x over previous
//
#include <hip/hip_runtime.h>
#include <stdint.h>

#define NB 128   // batch
#define NT 512   // time steps
#define NI 256   // input dim
#define NH 512   // hidden dim
#define NO 256   // output dim

// ---------- bf16 helpers ----------
__device__ __forceinline__ uint16_t f2bf(float x) {
  uint32_t u = __float_as_uint(x);
  return (uint16_t)((u + 0x7fffu + ((u >> 16) & 1u)) >> 16);
}
__device__ __forceinline__ uint32_t pack2bf(float a, float b) {
  return (uint32_t)f2bf(a) | ((uint32_t)f2bf(b) << 16);
}

__device__ __forceinline__ float fast_tanh(float x) {
  float e = __expf(2.0f * x);
#if __has_builtin(__builtin_amdgcn_rcpf)
  return 1.0f - 2.0f * __builtin_amdgcn_rcpf(e + 1.0f);
#else
  return 1.0f - 2.0f / (e + 1.0f);
#endif
}

typedef __bf16 bf16x8 __attribute__((ext_vector_type(8)));
typedef float f32x4 __attribute__((ext_vector_type(4)));

__device__ __forceinline__ f32x4 mfma16(bf16x8 a, uint4 b, f32x4 c) {
  return __builtin_amdgcn_mfma_f32_16x16x32_bf16(a, __builtin_bit_cast(bf16x8, b), c, 0, 0, 0);
}

// ---------- kernel 0: pack W_hh B-frags; Wih->frag order; transpose W_out; bias sum ----------
// recur thread t (0..511): wave w=t>>6, sl=t&15, quad=(t>>4)&3.
// B-frag quad q = u*16 + tk (u=n-tile 0..3, tk=k-tile 0..15):
//   n = w*64 + u*16 + sl, k = tk*32 + quad*8 + j (j=0..7), value W_hh[n][k].
// Stored WB[q*512 + t] (uint4, lane-coalesced). q<52 -> regs, q>=52 -> LDS.
// xproj A-frag WihF[(u*8+k0)*64 + l]: row n=u*16+(l&15), k=k0*32+(l>>4)*8+j.
__global__ __launch_bounds__(256) void prep_kernel(const float* __restrict__ Whh,
                                                   const float* __restrict__ Wih,
                                                   const float* __restrict__ Wout,
                                                   const float* __restrict__ bih,
                                                   const float* __restrict__ bhh,
                                                   uint4* __restrict__ WB,
                                                   float* __restrict__ WoT,
                                                   uint4* __restrict__ WihF,
                                                   float* __restrict__ BS) {
  int idx = blockIdx.x * 256 + threadIdx.x;
  if (idx < 32768) {                       // W_hh B-fragments
    int q = idx >> 9, t = idx & 511;
    int u = q >> 4, tk = q & 15;
    int n = (t >> 6) * 64 + u * 16 + (t & 15);
    int kb = tk * 32 + ((t >> 4) & 3) * 8;
    const float* row = Whh + (size_t)n * NH + kb;
    float4 f0 = *(const float4*)row;
    float4 f1 = *(const float4*)(row + 4);
    uint4 wq;
    wq.x = pack2bf(f0.x, f0.y);
    wq.y = pack2bf(f0.z, f0.w);
    wq.z = pack2bf(f1.x, f1.y);
    wq.w = pack2bf(f1.z, f1.w);
    WB[idx] = wq;
  } else if (idx < 49152) {                // Wih A-fragments (for xproj arg0)
    int i = idx - 32768;
    int l = i & 63;
    int uk = i >> 6;                       // 0..255
    int k0 = uk & 7, u = uk >> 3;
    int n = u * 16 + (l & 15);
    int kb = k0 * 32 + (l >> 4) * 8;
    const float* row = Wih + (size_t)n * NI + kb;
    float4 f0 = *(const float4*)row;
    float4 f1 = *(const float4*)(row + 4);
    uint4 wq;
    wq.x = pack2bf(f0.x, f0.y);
    wq.y = pack2bf(f0.z, f0.w);
    wq.z = pack2bf(f1.x, f1.y);
    wq.w = pack2bf(f1.z, f1.w);
    WihF[i] = wq;
  } else if (idx < 81920) {                // W_out transpose (fp32)
    int i = idx - 49152;
    int o4 = (i & 63) * 4;
    int k = i >> 6;
    float4 v;
    v.x = Wout[(size_t)(o4 + 0) * NH + k];
    v.y = Wout[(size_t)(o4 + 1) * NH + k];
    v.z = Wout[(size_t)(o4 + 2) * NH + k];
    v.w = Wout[(size_t)(o4 + 3) * NH + k];
    *(float4*)&WoT[(size_t)k * NO + o4] = v;
  } else if (idx < 82432) {                // bias sum
    int n = idx - 81920;
    BS[n] = bih[n] + bhh[n];
  }
}

// ---------- kernel 1: x_proj GEMM via bf16 MFMA, frag-swizzled B ----------
__global__ __launch_bounds__(256, 2) void xproj_kernel(const float* __restrict__ A,
                                                       const uint4* __restrict__ WihF,
                                                       const float* __restrict__ BS,
                                                       uint16_t* __restrict__ XP) {
  const int w = threadIdx.x >> 6;
  const int l = threadIdx.x & 63;
  const int sl = l & 15, quad = l >> 4;
  const int m = blockIdx.x * 64 + w * 16 + sl;   // input row this lane supplies

  f32x4 acc[32] = {};
  const float* arow = A + (size_t)m * NI;

  for (int k0 = 0; k0 < 8; ++k0) {
    float4 f0 = *(const float4*)(arow + k0 * 32 + quad * 8);
    float4 f1 = *(const float4*)(arow + k0 * 32 + quad * 8 + 4);
    uint4 ap;
    ap.x = pack2bf(f0.x, f0.y);
    ap.y = pack2bf(f0.z, f0.w);
    ap.z = pack2bf(f1.x, f1.y);
    ap.w = pack2bf(f1.z, f1.w);
    bf16x8 afrag = __builtin_bit_cast(bf16x8, ap);
#pragma unroll
    for (int u = 0; u < 32; ++u) {
      uint4 bp = WihF[(u * 8 + k0) * 64 + l];    // lane-coalesced, L2-resident
      acc[u] = __builtin_amdgcn_mfma_f32_16x16x32_bf16(
          __builtin_bit_cast(bf16x8, bp), afrag, acc[u], 0, 0, 0);
    }
  }

  uint16_t* xrow = XP + (size_t)m * NH;
#pragma unroll
  for (int u = 0; u < 32; ++u) {
    float4 bs = *(const float4*)(BS + u * 16 + quad * 4);
    uint2 pw;
    pw.x = pack2bf(acc[u][0] + bs.x, acc[u][1] + bs.y);
    pw.y = pack2bf(acc[u][2] + bs.z, acc[u][3] + bs.w);
    *(uint2*)(xrow + u * 16 + quad * 4) = pw;
  }
}

// ---------- kernel 2: recurrence via MFMA (A-replication), 1 barrier/step ----------
// 128 WGs x 512 thr (8 waves, 2/SIMD). Wave w owns outputs [w*64, w*64+64):
// 4 n-tiles (u=quad-selected at epilogue) x 16 k-tiles, k-reduce inside MFMA.
// A-frag: every lane's 8 elems = h[tk*32 + quad*8 + j] -> all D rows equal y.
__global__ __launch_bounds__(512, 2) void recur_kernel(const uint4* __restrict__ WB,
                                                       const float* __restrict__ WoT,
                                                       const uint16_t* __restrict__ XP,
                                                       const float* __restrict__ h0,
                                                       const float* __restrict__ bout,
                                                       float* __restrict__ out) {
  __shared__ uint4 WL[12][512];                  // 96 KB: quads q=52..63 (u=3, tk=4..15)
  __shared__ __align__(16) uint16_t h2[2][NH];   // 2 KB: bf16 h, double-buffered
  __shared__ float hsf[NH];                      // 2 KB: fp32 h for readout
  const int t = threadIdx.x;
  const int b = blockIdx.x;
  const int w = t >> 6;
  const int sl = t & 15, quad = (t >> 4) & 3;
  const int myn = w * 64 + quad * 16 + sl;       // h element this lane owns
  const float invT = 1.0f / (float)NT;

  uint4 Wr[52];
#pragma unroll
  for (int q = 0; q < 52; ++q) Wr[q] = WB[q * 512 + t];
#pragma unroll
  for (int i = 0; i < 12; ++i) WL[i][t] = WB[(52 + i) * 512 + t];

  float hj = h0[myn];
  h2[0][myn] = f2bf(hj);
  __syncthreads();

  const uint16_t* xpb = XP + (size_t)b * NT * NH + myn;

  for (int ts = 0; ts < NT; ++ts) {
    const int cur = ts & 1;
    float xpj = __uint_as_float((uint32_t)xpb[(size_t)ts * NH] << 16);

    const uint16_t* hbuf = h2[cur];
    f32x4 acc0 = {}, acc1 = {}, acc2 = {}, acc3 = {};
#pragma unroll
    for (int tk = 0; tk < 16; ++tk) {
      bf16x8 hfrag = *(const bf16x8*)(hbuf + tk * 32 + quad * 8);  // 16B, quad-addressed
      acc0 = mfma16(hfrag, Wr[tk], acc0);
      acc1 = mfma16(hfrag, Wr[16 + tk], acc1);
      acc2 = mfma16(hfrag, Wr[32 + tk], acc2);
      uint4 w3 = (tk < 4) ? Wr[48 + tk] : WL[tk - 4][t];
      acc3 = mfma16(hfrag, w3, acc3);
    }
    // all D rows identical; lane's owned n = w*64 + quad*16 + sl -> tile u = quad
    float y = (quad == 0) ? acc0[0] : (quad == 1) ? acc1[0] : (quad == 2) ? acc2[0] : acc3[0];
    float hnew = fmaf(fast_tanh(xpj + y), invT, hj);
    hj = hnew;
    h2[cur ^ 1][myn] = f2bf(hnew);
    __syncthreads();   // publish h[nxt]; reads of h[cur] are done (other buffer)
  }

  hsf[myn] = hj;
  __syncthreads();

  if (t < NO) {
    float c0 = 0.f, c1 = 0.f;
#pragma unroll 4
    for (int k = 0; k < NH; k += 2) {
      c0 = fmaf(WoT[(size_t)k * NO + t], hsf[k], c0);
      c1 = fmaf(WoT[(size_t)(k + 1) * NO + t], hsf[k + 1], c1);
    }
    out[(size_t)b * NO + t] = c0 + c1 + bout[t];
  }
}

// ---------- launch ----------
extern "C" void kernel_launch(void* const* d_in, const int* in_sizes, int n_in,
                              void* d_out, int out_size, void* d_ws, size_t ws_size,
                              hipStream_t stream) {
  const float* inputs = (const float*)d_in[0];
  const float* Wih    = (const float*)d_in[1];
  const float* bih    = (const float*)d_in[2];
  const float* Whh    = (const float*)d_in[3];
  const float* bhh    = (const float*)d_in[4];
  const float* Wout   = (const float*)d_in[5];
  const float* bout   = (const float*)d_in[6];
  const float* h0     = (const float*)d_in[7];
  float* out = (float*)d_out;

  char* ws = (char*)d_ws;
  uint4*    WB   = (uint4*)ws;                          // 512 KB: W_hh B-frags
  float*    WoT  = (float*)(ws + (512u << 10));         // 512 KB: W_out^T
  uint4*    WihF = (uint4*)(ws + (1024u << 10));        // 256 KB: Wih A-frags
  float*    BS   = (float*)(ws + (1280u << 10));        // 2 KB: bias sum
  uint16_t* XP   = (uint16_t*)(ws + (1536u << 10));     // 64 MB: x_proj bf16

  hipLaunchKernelGGL(prep_kernel, dim3(322), dim3(256), 0, stream,
                     Whh, Wih, Wout, bih, bhh, WB, WoT, WihF, BS);
  hipLaunchKernelGGL(xproj_kernel, dim3(NB * NT / 64), dim3(256), 0, stream,
                     inputs, WihF, BS, XP);
  hipLaunchKernelGGL(recur_kernel, dim3(NB), dim3(512), 0, stream,
                     WB, WoT, XP, h0, bout, out);
}